// Round 1
// baseline (5496.601 us; speedup 1.0000x reference)
//
#include <hip/hip_runtime.h>
#include <math.h>

#define NN 50000
#define NE 800000
#define FIN 64
#define HD 200
#define NG 256

// ---------- setup kernels ----------
__global__ void k_deg(const int* __restrict__ src, float* __restrict__ deg, int E) {
    int e = blockIdx.x * blockDim.x + threadIdx.x;
    if (e < E) atomicAdd(&deg[src[e]], 1.0f);
}

__global__ void k_node_prep(float* __restrict__ degdis, const int* __restrict__ batch,
                            const float* __restrict__ lmax, float* __restrict__ diag, int n) {
    int i = blockIdx.x * blockDim.x + threadIdx.x;
    if (i < n) {
        float d = degdis[i];
        degdis[i] = (d > 0.f) ? (1.0f / sqrtf(fmaxf(d, 1.0f))) : 0.0f;   // dis
        diag[i] = 2.0f / lmax[batch[i]] - 1.0f;
    }
}

__global__ void k_edge_w(const int* __restrict__ src, const int* __restrict__ dst,
                         const int* __restrict__ batch, const float* __restrict__ lmax,
                         const float* __restrict__ dis, float* __restrict__ w, int E) {
    int e = blockIdx.x * blockDim.x + threadIdx.x;
    if (e < E) {
        int s = src[e], d = dst[e];
        w[e] = -dis[s] * dis[d] * (2.0f / lmax[batch[s]]);
    }
}

// ---------- propagation: scatter w*h[src] -> out[dst]  (one wave per edge) ----------
__global__ void k_scatter(const int* __restrict__ src, const int* __restrict__ dst,
                          const float* __restrict__ w, const float* __restrict__ hin,
                          float* __restrict__ hout, int E, int F) {
    int e = blockIdx.x * 4 + (threadIdx.x >> 6);
    int lane = threadIdx.x & 63;
    if (e >= E) return;
    int s = src[e], d = dst[e];
    float we = w[e];
    const float* hs = hin + (size_t)s * F;
    float* hd = hout + (size_t)d * F;
    for (int f = lane; f < F; f += 64)
        atomicAdd(&hd[f], we * hs[f]);
}

// out[i,f] += diag[i] * in[i,f]
__global__ void k_add_diag(const float* __restrict__ diag, const float* __restrict__ in,
                           float* __restrict__ out, int n, int F) {
    int idx = blockIdx.x * blockDim.x + threadIdx.x;
    if (idx < n * F) {
        int i = idx / F;
        out[idx] += diag[i] * in[idx];
    }
}

// tx2[i,f] = 2*(tx2[i,f] + diag[i]*tx1[i,f]) - tx0[i,f]
__global__ void k_finish_tx2(const float* __restrict__ diag, const float* __restrict__ tx1,
                             const float* __restrict__ tx0, float* __restrict__ tx2,
                             int n, int F) {
    int idx = blockIdx.x * blockDim.x + threadIdx.x;
    if (idx < n * F) {
        int i = idx / F;
        tx2[idx] = 2.0f * (tx2[idx] + diag[i] * tx1[idx]) - tx0[idx];
    }
}

// ---------- fused Chebyshev GEMM: out = relu(Tx0@W0 + Tx1@W1 + Tx2@W2 + b) ----------
// 8 rows per block, 256 threads (j = column, 200 active for compute)
__global__ __launch_bounds__(256) void k_cheb_gemm(
    const float* __restrict__ tx0, const float* __restrict__ tx1, const float* __restrict__ tx2,
    const float* __restrict__ W, const float* __restrict__ b,
    float* __restrict__ out, int Fin) {
    __shared__ float t0[8][HD];
    __shared__ float t1[8][HD];
    __shared__ float t2[8][HD];
    int row0 = blockIdx.x * 8;
    int tid = threadIdx.x;
    int tot = 8 * Fin;
    for (int idx = tid; idx < tot; idx += 256) {
        int r = idx / Fin, k = idx - r * Fin;
        size_t g = (size_t)(row0 + r) * Fin + k;
        t0[r][k] = tx0[g];
        t1[r][k] = tx1[g];
        t2[r][k] = tx2[g];
    }
    __syncthreads();
    int j = tid;
    if (j < HD) {
        const float* W0 = W;
        const float* W1 = W + (size_t)Fin * HD;
        const float* W2 = W + 2 * (size_t)Fin * HD;
        float acc[8];
#pragma unroll
        for (int r = 0; r < 8; r++) acc[r] = 0.0f;
        for (int k = 0; k < Fin; k += 4) {
            const float* p0 = &W0[k * HD + j];
            const float* p1 = &W1[k * HD + j];
            const float* p2 = &W2[k * HD + j];
            float w00 = p0[0], w01 = p0[HD], w02 = p0[2 * HD], w03 = p0[3 * HD];
            float w10 = p1[0], w11 = p1[HD], w12 = p1[2 * HD], w13 = p1[3 * HD];
            float w20 = p2[0], w21 = p2[HD], w22 = p2[2 * HD], w23 = p2[3 * HD];
#pragma unroll
            for (int r = 0; r < 8; r++) {
                float4 a0 = *(const float4*)&t0[r][k];
                float4 a1 = *(const float4*)&t1[r][k];
                float4 a2 = *(const float4*)&t2[r][k];
                acc[r] += a0.x * w00 + a0.y * w01 + a0.z * w02 + a0.w * w03
                        + a1.x * w10 + a1.y * w11 + a1.z * w12 + a1.w * w13
                        + a2.x * w20 + a2.y * w21 + a2.z * w22 + a2.w * w23;
            }
        }
        float bj = b[j];
#pragma unroll
        for (int r = 0; r < 8; r++)
            out[(size_t)(row0 + r) * HD + j] = fmaxf(acc[r] + bj, 0.0f);
    }
}

// ---------- pooling: one wave per node ----------
__global__ void k_pool(const float* __restrict__ h, const int* __restrict__ batch,
                       float* __restrict__ psum, float* __restrict__ pmax,
                       float* __restrict__ cnt, int n) {
    int i = blockIdx.x * 4 + (threadIdx.x >> 6);
    int lane = threadIdx.x & 63;
    if (i >= n) return;
    int g = batch[i];
    if (lane == 0) atomicAdd(&cnt[g], 1.0f);
    const float* hr = h + (size_t)i * HD;
    for (int f = lane; f < HD; f += 64) {
        float v = hr[f];
        atomicAdd(&psum[g * HD + f], v);
        atomicMax((unsigned int*)&pmax[g * HD + f], __float_as_uint(v));  // v >= 0 post-ReLU
    }
}

// ---------- FC + log_softmax: one wave (64 threads) per graph ----------
__global__ void k_fc(const float* __restrict__ psum, const float* __restrict__ pmax,
                     const float* __restrict__ cnt, const float* __restrict__ fcw,
                     const float* __restrict__ fcb, float* __restrict__ out) {
    int g = blockIdx.x;
    int lane = threadIdx.x;
    float inv = 1.0f / fmaxf(cnt[g], 1.0f);
    float z0 = 0.0f, z1 = 0.0f;
    for (int j = lane; j < HD; j += 64) {
        float m = psum[g * HD + j] * inv;
        float M = pmax[g * HD + j];
        z0 += m * fcw[j * 2 + 0] + M * fcw[(HD + j) * 2 + 0];
        z1 += m * fcw[j * 2 + 1] + M * fcw[(HD + j) * 2 + 1];
    }
#pragma unroll
    for (int o = 32; o > 0; o >>= 1) {
        z0 += __shfl_down(z0, o);
        z1 += __shfl_down(z1, o);
    }
    if (lane == 0) {
        z0 += fcb[0];
        z1 += fcb[1];
        float m = fmaxf(z0, z1);
        float lse = m + logf(expf(z0 - m) + expf(z1 - m));
        out[g * 2 + 0] = z0 - lse;
        out[g * 2 + 1] = z1 - lse;
    }
}

extern "C" void kernel_launch(void* const* d_in, const int* in_sizes, int n_in,
                              void* d_out, int out_size, void* d_ws, size_t ws_size,
                              hipStream_t stream) {
    const float* x     = (const float*)d_in[0];
    const int*   edge  = (const int*)d_in[1];
    const int*   batch = (const int*)d_in[2];
    const float* lmax  = (const float*)d_in[3];
    const float* W1 = (const float*)d_in[4];  const float* b1 = (const float*)d_in[5];
    const float* W2 = (const float*)d_in[6];  const float* b2 = (const float*)d_in[7];
    const float* W3 = (const float*)d_in[8];  const float* b3 = (const float*)d_in[9];
    const float* W4 = (const float*)d_in[10]; const float* b4 = (const float*)d_in[11];
    const float* fcw = (const float*)d_in[12]; const float* fcb = (const float*)d_in[13];
    float* out = (float*)d_out;

    const int n = NN, E = NE;
    const int* src = edge;
    const int* dst = edge + E;

    // workspace layout (floats)
    float* ws = (float*)d_ws;
    size_t off = 0;
    float* dis  = ws + off; off += NN;        // deg -> dis in place
    float* diag = ws + off; off += NN;
    float* wE   = ws + off; off += NE;
    float* cnt  = ws + off; off += NG;
    float* psum = ws + off; off += (size_t)NG * HD;
    float* pmax = ws + off; off += (size_t)NG * HD;
    float* A = ws + off; off += (size_t)NN * HD;
    float* B = ws + off; off += (size_t)NN * HD;
    float* C = ws + off; off += (size_t)NN * HD;
    float* D = ws + off; off += (size_t)NN * HD;

    dim3 blk(256);
    int gE = (E + 255) / 256;
    int gN = (n + 255) / 256;
    int gE4 = (E + 3) / 4;     // wave-per-edge blocks
    int gN4 = (n + 3) / 4;     // wave-per-node blocks

    // --- graph normalization precompute ---
    hipMemsetAsync(dis, 0, (size_t)NN * 4, stream);
    k_deg<<<gE, blk, 0, stream>>>(src, dis, E);
    k_node_prep<<<gN, blk, 0, stream>>>(dis, batch, lmax, diag, n);
    k_edge_w<<<gE, blk, 0, stream>>>(src, dst, batch, lmax, dis, wE, E);

    // --- 4 Chebyshev layers ---
    struct Layer { const float* tx0; const float* W; const float* b; float* outp; int Fin; };
    Layer layers[4] = {
        { x, W1, b1, A, FIN },
        { A, W2, b2, D, HD },
        { D, W3, b3, A, HD },
        { A, W4, b4, D, HD },
    };
    for (int l = 0; l < 4; l++) {
        const float* tx0 = layers[l].tx0;
        int Fin = layers[l].Fin;
        size_t nbytes = (size_t)n * Fin * 4;
        int gNF = (n * Fin + 255) / 256;

        // Tx1 = prop(tx0)
        hipMemsetAsync(B, 0, nbytes, stream);
        k_scatter<<<gE4, blk, 0, stream>>>(src, dst, wE, tx0, B, E, Fin);
        k_add_diag<<<gNF, blk, 0, stream>>>(diag, tx0, B, n, Fin);
        // Tx2 = 2*prop(Tx1) - tx0
        hipMemsetAsync(C, 0, nbytes, stream);
        k_scatter<<<gE4, blk, 0, stream>>>(src, dst, wE, B, C, E, Fin);
        k_finish_tx2<<<gNF, blk, 0, stream>>>(diag, B, tx0, C, n, Fin);
        // out = relu(Tx0@W0 + Tx1@W1 + Tx2@W2 + b)
        k_cheb_gemm<<<(n + 7) / 8, blk, 0, stream>>>(tx0, B, C, layers[l].W, layers[l].b,
                                                     layers[l].outp, Fin);
    }

    // --- pooling + FC head ---
    hipMemsetAsync(psum, 0, (size_t)NG * HD * 4, stream);
    hipMemsetAsync(pmax, 0, (size_t)NG * HD * 4, stream);
    hipMemsetAsync(cnt, 0, (size_t)NG * 4, stream);
    k_pool<<<gN4, blk, 0, stream>>>(D, batch, psum, pmax, cnt, n);
    k_fc<<<NG, dim3(64), 0, stream>>>(psum, pmax, cnt, fcw, fcb, out);
}

// Round 2
// 2402.546 us; speedup vs baseline: 2.2878x; 2.2878x over previous
//
#include <hip/hip_runtime.h>
#include <math.h>

#define NN 50000
#define NE 800000
#define FIN 64
#define HD 200
#define NG 256
#define SCAN_B 256

// ---------- setup: src out-degree (float, for norm) + dst in-degree (int, for CSR) ----------
__global__ void k_deg(const int* __restrict__ src, const int* __restrict__ dst,
                      float* __restrict__ deg, int* __restrict__ cnt_dst, int E) {
    int e = blockIdx.x * blockDim.x + threadIdx.x;
    if (e < E) {
        atomicAdd(&deg[src[e]], 1.0f);
        atomicAdd(&cnt_dst[dst[e]], 1);
    }
}

__global__ void k_node_prep(float* __restrict__ degdis, const int* __restrict__ batch,
                            const float* __restrict__ lmax, float* __restrict__ diag, int n) {
    int i = blockIdx.x * blockDim.x + threadIdx.x;
    if (i < n) {
        float d = degdis[i];
        degdis[i] = (d > 0.f) ? (1.0f / sqrtf(fmaxf(d, 1.0f))) : 0.0f;   // dis
        diag[i] = 2.0f / lmax[batch[i]] - 1.0f;
    }
}

__global__ void k_edge_w(const int* __restrict__ src, const int* __restrict__ dst,
                         const int* __restrict__ batch, const float* __restrict__ lmax,
                         const float* __restrict__ dis, float* __restrict__ w, int E) {
    int e = blockIdx.x * blockDim.x + threadIdx.x;
    if (e < E) {
        int s = src[e], d = dst[e];
        w[e] = -dis[s] * dis[d] * (2.0f / lmax[batch[s]]);
    }
}

// ---------- exclusive scan over cnt_dst (3-kernel hierarchical) ----------
__global__ void k_scan1(const int* __restrict__ cnt, int* __restrict__ excl,
                        int* __restrict__ bsum, int n) {
    __shared__ int sh[SCAN_B];
    int tid = threadIdx.x;
    int i = blockIdx.x * SCAN_B + tid;
    int v = (i < n) ? cnt[i] : 0;
    sh[tid] = v;
    __syncthreads();
    for (int off = 1; off < SCAN_B; off <<= 1) {
        int t = (tid >= off) ? sh[tid - off] : 0;
        __syncthreads();
        sh[tid] += t;
        __syncthreads();
    }
    if (i < n) excl[i] = sh[tid] - v;
    if (tid == SCAN_B - 1) bsum[blockIdx.x] = sh[tid];
}

__global__ void k_scan2(int* __restrict__ bsum, int nb) {
    __shared__ int sh[SCAN_B];
    int tid = threadIdx.x;
    int v = (tid < nb) ? bsum[tid] : 0;
    sh[tid] = v;
    __syncthreads();
    for (int off = 1; off < SCAN_B; off <<= 1) {
        int t = (tid >= off) ? sh[tid - off] : 0;
        __syncthreads();
        sh[tid] += t;
        __syncthreads();
    }
    if (tid < nb) bsum[tid] = sh[tid] - v;   // exclusive
}

__global__ void k_scan3(int* __restrict__ excl, const int* __restrict__ bsum, int n) {
    int i = blockIdx.x * SCAN_B + threadIdx.x;
    if (i < n) excl[i] += bsum[blockIdx.x];
}

// ---------- permute edges into CSR-by-dst order ----------
__global__ void k_fillcsr(const int* __restrict__ src, const int* __restrict__ dst,
                          const float* __restrict__ w, const int* __restrict__ rowstart,
                          int* __restrict__ fill, int* __restrict__ csr_src,
                          float* __restrict__ csr_w, int E) {
    int e = blockIdx.x * blockDim.x + threadIdx.x;
    if (e < E) {
        int d = dst[e];
        int pos = rowstart[d] + atomicAdd(&fill[d], 1);
        csr_src[pos] = src[e];
        csr_w[pos] = w[e];
    }
}

// ---------- propagation (gather): one wave per node ----------
// mode 0: out = gath + diag*hin                      (Tx1)
// mode 1: out = 2*(gath + diag*hin) - hin0           (Tx2 finish)
__global__ __launch_bounds__(256) void k_gather(
    const int* __restrict__ rowstart, const int* __restrict__ rowcnt,
    const int* __restrict__ csr_src, const float* __restrict__ csr_w,
    const float* __restrict__ diag, const float* __restrict__ hin,
    const float* __restrict__ hin0, float* __restrict__ hout,
    int n, int F, int mode) {
    int i = blockIdx.x * 4 + (threadIdx.x >> 6);
    if (i >= n) return;
    int lane = threadIdx.x & 63;
    int start = rowstart[i], cnt = rowcnt[i];
    float acc[4] = {0.f, 0.f, 0.f, 0.f};
    int k = 0;
    for (; k + 1 < cnt; k += 2) {
        int s0 = csr_src[start + k], s1 = csr_src[start + k + 1];
        float w0 = csr_w[start + k], w1 = csr_w[start + k + 1];
        const float* h0 = hin + (size_t)s0 * F;
        const float* h1 = hin + (size_t)s1 * F;
#pragma unroll
        for (int j = 0; j < 4; ++j) {
            int f = lane + (j << 6);
            if (f < F) acc[j] += w0 * h0[f] + w1 * h1[f];
        }
    }
    if (k < cnt) {
        int s0 = csr_src[start + k];
        float w0 = csr_w[start + k];
        const float* h0 = hin + (size_t)s0 * F;
#pragma unroll
        for (int j = 0; j < 4; ++j) {
            int f = lane + (j << 6);
            if (f < F) acc[j] += w0 * h0[f];
        }
    }
    float dg = diag[i];
    const float* hi = hin + (size_t)i * F;
    float* ho = hout + (size_t)i * F;
    if (mode == 0) {
#pragma unroll
        for (int j = 0; j < 4; ++j) {
            int f = lane + (j << 6);
            if (f < F) ho[f] = acc[j] + dg * hi[f];
        }
    } else {
        const float* h0p = hin0 + (size_t)i * F;
#pragma unroll
        for (int j = 0; j < 4; ++j) {
            int f = lane + (j << 6);
            if (f < F) ho[f] = 2.0f * (acc[j] + dg * hi[f]) - h0p[f];
        }
    }
}

// ---------- fused Chebyshev GEMM: out = relu(Tx0@W0 + Tx1@W1 + Tx2@W2 + b) ----------
__global__ __launch_bounds__(256) void k_cheb_gemm(
    const float* __restrict__ tx0, const float* __restrict__ tx1, const float* __restrict__ tx2,
    const float* __restrict__ W, const float* __restrict__ b,
    float* __restrict__ out, int Fin) {
    __shared__ float t0[8][HD];
    __shared__ float t1[8][HD];
    __shared__ float t2[8][HD];
    int row0 = blockIdx.x * 8;
    int tid = threadIdx.x;
    int tot = 8 * Fin;
    for (int idx = tid; idx < tot; idx += 256) {
        int r = idx / Fin, k = idx - r * Fin;
        size_t g = (size_t)(row0 + r) * Fin + k;
        t0[r][k] = tx0[g];
        t1[r][k] = tx1[g];
        t2[r][k] = tx2[g];
    }
    __syncthreads();
    int j = tid;
    if (j < HD) {
        const float* W0 = W;
        const float* W1 = W + (size_t)Fin * HD;
        const float* W2 = W + 2 * (size_t)Fin * HD;
        float acc[8];
#pragma unroll
        for (int r = 0; r < 8; r++) acc[r] = 0.0f;
        for (int k = 0; k < Fin; k += 4) {
            const float* p0 = &W0[k * HD + j];
            const float* p1 = &W1[k * HD + j];
            const float* p2 = &W2[k * HD + j];
            float w00 = p0[0], w01 = p0[HD], w02 = p0[2 * HD], w03 = p0[3 * HD];
            float w10 = p1[0], w11 = p1[HD], w12 = p1[2 * HD], w13 = p1[3 * HD];
            float w20 = p2[0], w21 = p2[HD], w22 = p2[2 * HD], w23 = p2[3 * HD];
#pragma unroll
            for (int r = 0; r < 8; r++) {
                float4 a0 = *(const float4*)&t0[r][k];
                float4 a1 = *(const float4*)&t1[r][k];
                float4 a2 = *(const float4*)&t2[r][k];
                acc[r] += a0.x * w00 + a0.y * w01 + a0.z * w02 + a0.w * w03
                        + a1.x * w10 + a1.y * w11 + a1.z * w12 + a1.w * w13
                        + a2.x * w20 + a2.y * w21 + a2.z * w22 + a2.w * w23;
            }
        }
        float bj = b[j];
#pragma unroll
        for (int r = 0; r < 8; r++)
            out[(size_t)(row0 + r) * HD + j] = fmaxf(acc[r] + bj, 0.0f);
    }
}

// ---------- pooling: one wave per node ----------
__global__ void k_pool(const float* __restrict__ h, const int* __restrict__ batch,
                       float* __restrict__ psum, float* __restrict__ pmax,
                       float* __restrict__ cnt, int n) {
    int i = blockIdx.x * 4 + (threadIdx.x >> 6);
    int lane = threadIdx.x & 63;
    if (i >= n) return;
    int g = batch[i];
    if (lane == 0) atomicAdd(&cnt[g], 1.0f);
    const float* hr = h + (size_t)i * HD;
    for (int f = lane; f < HD; f += 64) {
        float v = hr[f];
        atomicAdd(&psum[g * HD + f], v);
        atomicMax((unsigned int*)&pmax[g * HD + f], __float_as_uint(v));  // v >= 0 post-ReLU
    }
}

// ---------- FC + log_softmax: one wave per graph ----------
__global__ void k_fc(const float* __restrict__ psum, const float* __restrict__ pmax,
                     const float* __restrict__ cnt, const float* __restrict__ fcw,
                     const float* __restrict__ fcb, float* __restrict__ out) {
    int g = blockIdx.x;
    int lane = threadIdx.x;
    float inv = 1.0f / fmaxf(cnt[g], 1.0f);
    float z0 = 0.0f, z1 = 0.0f;
    for (int j = lane; j < HD; j += 64) {
        float m = psum[g * HD + j] * inv;
        float M = pmax[g * HD + j];
        z0 += m * fcw[j * 2 + 0] + M * fcw[(HD + j) * 2 + 0];
        z1 += m * fcw[j * 2 + 1] + M * fcw[(HD + j) * 2 + 1];
    }
#pragma unroll
    for (int o = 32; o > 0; o >>= 1) {
        z0 += __shfl_down(z0, o);
        z1 += __shfl_down(z1, o);
    }
    if (lane == 0) {
        z0 += fcb[0];
        z1 += fcb[1];
        float m = fmaxf(z0, z1);
        float lse = m + logf(expf(z0 - m) + expf(z1 - m));
        out[g * 2 + 0] = z0 - lse;
        out[g * 2 + 1] = z1 - lse;
    }
}

extern "C" void kernel_launch(void* const* d_in, const int* in_sizes, int n_in,
                              void* d_out, int out_size, void* d_ws, size_t ws_size,
                              hipStream_t stream) {
    const float* x     = (const float*)d_in[0];
    const int*   edge  = (const int*)d_in[1];
    const int*   batch = (const int*)d_in[2];
    const float* lmax  = (const float*)d_in[3];
    const float* W1 = (const float*)d_in[4];  const float* b1 = (const float*)d_in[5];
    const float* W2 = (const float*)d_in[6];  const float* b2 = (const float*)d_in[7];
    const float* W3 = (const float*)d_in[8];  const float* b3 = (const float*)d_in[9];
    const float* W4 = (const float*)d_in[10]; const float* b4 = (const float*)d_in[11];
    const float* fcw = (const float*)d_in[12]; const float* fcb = (const float*)d_in[13];
    float* out = (float*)d_out;

    const int n = NN, E = NE;
    const int* src = edge;
    const int* dst = edge + E;

    // workspace layout (4-byte units)
    float* ws = (float*)d_ws;
    size_t off = 0;
    float* dis    = ws + off; off += NN;        // deg -> dis in place
    float* diag   = ws + off; off += NN;
    float* wE     = ws + off; off += NE;
    int*   cntd   = (int*)(ws + off); off += NN;   // dst in-degree
    int*   rowst  = (int*)(ws + off); off += NN;   // exclusive scan
    int*   fill   = (int*)(ws + off); off += NN;
    int*   bsum   = (int*)(ws + off); off += SCAN_B;
    int*   csrs   = (int*)(ws + off); off += NE;
    float* csrw   = ws + off; off += NE;
    float* cnt    = ws + off; off += NG;
    float* psum   = ws + off; off += (size_t)NG * HD;
    float* pmax   = ws + off; off += (size_t)NG * HD;
    float* A = ws + off; off += (size_t)NN * HD;
    float* B = ws + off; off += (size_t)NN * HD;
    float* C = ws + off; off += (size_t)NN * HD;
    float* D = ws + off; off += (size_t)NN * HD;

    dim3 blk(256);
    int gE = (E + 255) / 256;
    int gN = (n + 255) / 256;
    int gScan = (n + SCAN_B - 1) / SCAN_B;   // 196
    int gN4 = (n + 3) / 4;                   // wave-per-node blocks

    // --- normalization + CSR build ---
    hipMemsetAsync(dis, 0, (size_t)NN * 4, stream);
    hipMemsetAsync(cntd, 0, (size_t)NN * 4, stream);
    hipMemsetAsync(fill, 0, (size_t)NN * 4, stream);
    k_deg<<<gE, blk, 0, stream>>>(src, dst, dis, cntd, E);
    k_node_prep<<<gN, blk, 0, stream>>>(dis, batch, lmax, diag, n);
    k_edge_w<<<gE, blk, 0, stream>>>(src, dst, batch, lmax, dis, wE, E);
    k_scan1<<<gScan, blk, 0, stream>>>(cntd, rowst, bsum, n);
    k_scan2<<<1, blk, 0, stream>>>(bsum, gScan);
    k_scan3<<<gScan, blk, 0, stream>>>(rowst, bsum, n);
    k_fillcsr<<<gE, blk, 0, stream>>>(src, dst, wE, rowst, fill, csrs, csrw, E);

    // --- 4 Chebyshev layers ---
    struct Layer { const float* tx0; const float* W; const float* b; float* outp; int Fin; };
    Layer layers[4] = {
        { x, W1, b1, A, FIN },
        { A, W2, b2, D, HD },
        { D, W3, b3, A, HD },
        { A, W4, b4, D, HD },
    };
    for (int l = 0; l < 4; l++) {
        const float* tx0 = layers[l].tx0;
        int Fin = layers[l].Fin;
        // Tx1 = prop(tx0)  (B)
        k_gather<<<gN4, blk, 0, stream>>>(rowst, cntd, csrs, csrw, diag, tx0, tx0, B, n, Fin, 0);
        // Tx2 = 2*prop(Tx1) - tx0  (C)
        k_gather<<<gN4, blk, 0, stream>>>(rowst, cntd, csrs, csrw, diag, B, tx0, C, n, Fin, 1);
        // out = relu(Tx0@W0 + Tx1@W1 + Tx2@W2 + b)
        k_cheb_gemm<<<(n + 7) / 8, blk, 0, stream>>>(tx0, B, C, layers[l].W, layers[l].b,
                                                     layers[l].outp, Fin);
    }

    // --- pooling + FC head ---
    hipMemsetAsync(psum, 0, (size_t)NG * HD * 4, stream);
    hipMemsetAsync(pmax, 0, (size_t)NG * HD * 4, stream);
    hipMemsetAsync(cnt, 0, (size_t)NG * 4, stream);
    k_pool<<<gN4, blk, 0, stream>>>(D, batch, psum, pmax, cnt, n);
    k_fc<<<NG, dim3(64), 0, stream>>>(psum, pmax, cnt, fcw, fcb, out);
}

// Round 3
// 2056.924 us; speedup vs baseline: 2.6722x; 1.1680x over previous
//
#include <hip/hip_runtime.h>
#include <math.h>

#define NN 50000
#define MP 50048          // NN padded to multiple of 128 (GEMM block rows)
#define NE 800000
#define FIN 64
#define HD 200
#define NG 256
#define SCAN_B 256
#define KPAD 224          // HD padded to multiple of 32 for MFMA K-steps
#define NT 13             // 13 * 16 = 208 >= 200 output col tiles
#define WT_STRIDE 36      // LDS k-stride (fp16 elems): 72B rows -> bank-spread

typedef _Float16 h16;
typedef __attribute__((ext_vector_type(8))) _Float16 half8;
typedef __attribute__((ext_vector_type(4))) float float4v;

// ---------- setup: src out-degree (float) + dst in-degree (int, for CSR) ----------
__global__ void k_deg(const int* __restrict__ src, const int* __restrict__ dst,
                      float* __restrict__ deg, int* __restrict__ cnt_dst, int E) {
    int e = blockIdx.x * blockDim.x + threadIdx.x;
    if (e < E) {
        atomicAdd(&deg[src[e]], 1.0f);
        atomicAdd(&cnt_dst[dst[e]], 1);
    }
}

__global__ void k_node_prep(float* __restrict__ degdis, const int* __restrict__ batch,
                            const float* __restrict__ lmax, float* __restrict__ diag, int n) {
    int i = blockIdx.x * blockDim.x + threadIdx.x;
    if (i < n) {
        float d = degdis[i];
        degdis[i] = (d > 0.f) ? (1.0f / sqrtf(fmaxf(d, 1.0f))) : 0.0f;   // dis
        diag[i] = 2.0f / lmax[batch[i]] - 1.0f;
    }
}

__global__ void k_edge_w(const int* __restrict__ src, const int* __restrict__ dst,
                         const int* __restrict__ batch, const float* __restrict__ lmax,
                         const float* __restrict__ dis, float* __restrict__ w, int E) {
    int e = blockIdx.x * blockDim.x + threadIdx.x;
    if (e < E) {
        int s = src[e], d = dst[e];
        w[e] = -dis[s] * dis[d] * (2.0f / lmax[batch[s]]);
    }
}

// ---------- exclusive scan over cnt_dst ----------
__global__ void k_scan1(const int* __restrict__ cnt, int* __restrict__ excl,
                        int* __restrict__ bsum, int n) {
    __shared__ int sh[SCAN_B];
    int tid = threadIdx.x;
    int i = blockIdx.x * SCAN_B + tid;
    int v = (i < n) ? cnt[i] : 0;
    sh[tid] = v;
    __syncthreads();
    for (int off = 1; off < SCAN_B; off <<= 1) {
        int t = (tid >= off) ? sh[tid - off] : 0;
        __syncthreads();
        sh[tid] += t;
        __syncthreads();
    }
    if (i < n) excl[i] = sh[tid] - v;
    if (tid == SCAN_B - 1) bsum[blockIdx.x] = sh[tid];
}

__global__ void k_scan2(int* __restrict__ bsum, int nb) {
    __shared__ int sh[SCAN_B];
    int tid = threadIdx.x;
    int v = (tid < nb) ? bsum[tid] : 0;
    sh[tid] = v;
    __syncthreads();
    for (int off = 1; off < SCAN_B; off <<= 1) {
        int t = (tid >= off) ? sh[tid - off] : 0;
        __syncthreads();
        sh[tid] += t;
        __syncthreads();
    }
    if (tid < nb) bsum[tid] = sh[tid] - v;   // exclusive
}

__global__ void k_scan3(int* __restrict__ excl, const int* __restrict__ bsum, int n) {
    int i = blockIdx.x * SCAN_B + threadIdx.x;
    if (i < n) excl[i] += bsum[blockIdx.x];
}

// ---------- permute edges into CSR-by-dst order ----------
__global__ void k_fillcsr(const int* __restrict__ src, const int* __restrict__ dst,
                          const float* __restrict__ w, const int* __restrict__ rowstart,
                          int* __restrict__ fill, int* __restrict__ csr_src,
                          float* __restrict__ csr_w, int E) {
    int e = blockIdx.x * blockDim.x + threadIdx.x;
    if (e < E) {
        int d = dst[e];
        int pos = rowstart[d] + atomicAdd(&fill[d], 1);
        csr_src[pos] = src[e];
        csr_w[pos] = w[e];
    }
}

// ---------- fp32 -> fp16 split for x ----------
__global__ void k_split(const float* __restrict__ x, h16* __restrict__ x16, int total) {
    int i = blockIdx.x * blockDim.x + threadIdx.x;
    if (i < total) x16[i] = (h16)x[i];
}

// ---------- propagation (gather): one wave per node ----------
// mode 0: v = gath + diag*hin          -> houtF (f32) + hout16 (fp16)
// mode 1: v = 2*(gath + diag*hin)-hin0 -> hout16 (fp16) only
__global__ __launch_bounds__(256) void k_gather(
    const int* __restrict__ rowstart, const int* __restrict__ rowcnt,
    const int* __restrict__ csr_src, const float* __restrict__ csr_w,
    const float* __restrict__ diag, const float* __restrict__ hin,
    const float* __restrict__ hin0, float* __restrict__ houtF,
    h16* __restrict__ hout16, int s16,
    int n, int F, int mode) {
    int i = blockIdx.x * 4 + (threadIdx.x >> 6);
    if (i >= n) return;
    int lane = threadIdx.x & 63;
    int start = rowstart[i], cnt = rowcnt[i];
    float acc[4] = {0.f, 0.f, 0.f, 0.f};
    int k = 0;
    for (; k + 1 < cnt; k += 2) {
        int s0 = csr_src[start + k], s1 = csr_src[start + k + 1];
        float w0 = csr_w[start + k], w1 = csr_w[start + k + 1];
        const float* h0 = hin + (size_t)s0 * F;
        const float* h1 = hin + (size_t)s1 * F;
#pragma unroll
        for (int j = 0; j < 4; ++j) {
            int f = lane + (j << 6);
            if (f < F) acc[j] += w0 * h0[f] + w1 * h1[f];
        }
    }
    if (k < cnt) {
        int s0 = csr_src[start + k];
        float w0 = csr_w[start + k];
        const float* h0 = hin + (size_t)s0 * F;
#pragma unroll
        for (int j = 0; j < 4; ++j) {
            int f = lane + (j << 6);
            if (f < F) acc[j] += w0 * h0[f];
        }
    }
    float dg = diag[i];
    const float* hi = hin + (size_t)i * F;
    h16* ho16 = hout16 + (size_t)i * s16;
    if (mode == 0) {
        float* hoF = houtF + (size_t)i * F;
#pragma unroll
        for (int j = 0; j < 4; ++j) {
            int f = lane + (j << 6);
            if (f < F) {
                float v = acc[j] + dg * hi[f];
                hoF[f] = v;
                ho16[f] = (h16)v;
            }
        }
    } else {
        const float* h0p = hin0 + (size_t)i * F;
#pragma unroll
        for (int j = 0; j < 4; ++j) {
            int f = lane + (j << 6);
            if (f < F) {
                float v = 2.0f * (acc[j] + dg * hi[f]) - h0p[f];
                ho16[f] = (h16)v;
            }
        }
    }
    // zero the K-pad region (keeps MFMA pad contributions exactly 0)
    for (int f = F + lane; f < s16; f += 64) ho16[f] = (h16)0.f;
}

// ---------- MFMA fp16 GEMM: out = relu([A0|A1|A2] @ W + b) ----------
// W is f32 [3][fin][HD]; A* are fp16 row-major with k-stride strideA.
// Block: 256 thr = 4 waves; each wave computes 32 rows x 208 cols.
__global__ __launch_bounds__(256) void k_gemm16(
    const h16* __restrict__ A0, const h16* __restrict__ A1, const h16* __restrict__ A2,
    int strideA, int fin,
    const float* __restrict__ W, const float* __restrict__ bias,
    float* __restrict__ outF, h16* __restrict__ out16, int n) {
    __shared__ h16 Wt[208 * WT_STRIDE];   // 14976 B, [n][k] k-contig
    int tid = threadIdx.x;
    int wave = tid >> 6, lane = tid & 63;
    int nq = lane & 15, quad = lane >> 4;
    int mrow = blockIdx.x * 128 + wave * 32;
    int ksteps = (fin + 31) / 32;
    const h16* Aseg[3] = {A0, A1, A2};

    float4v acc[2][NT];
#pragma unroll
    for (int r = 0; r < 2; r++)
#pragma unroll
        for (int t = 0; t < NT; t++) acc[r][t] = (float4v)0.f;

    for (int seg = 0; seg < 3; ++seg) {
        const h16* Ab = Aseg[seg];
        const float* Wb = W + (size_t)seg * fin * HD;
        for (int ks = 0; ks < ksteps; ++ks) {
            int k0 = ks * 32;
            __syncthreads();
            // stage W k-slab (32 x 208) to LDS transposed, f32->fp16, zero-padded
            for (int idx = tid; idx < 208 * 16; idx += 256) {
                int kk2 = idx / 208;            // 0..15 (pairs of k)
                int nn = idx % 208;
                int kg0 = k0 + 2 * kk2;
                float v0 = (nn < HD && kg0 < fin) ? Wb[(size_t)kg0 * HD + nn] : 0.f;
                float v1 = (nn < HD && kg0 + 1 < fin) ? Wb[(size_t)(kg0 + 1) * HD + nn] : 0.f;
                union { h16 h[2]; unsigned u; } p;
                p.h[0] = (h16)v0; p.h[1] = (h16)v1;
                *(unsigned*)&Wt[nn * WT_STRIDE + 2 * kk2] = p.u;
            }
            __syncthreads();
            half8 af[2];
#pragma unroll
            for (int r = 0; r < 2; ++r) {
                int row = mrow + r * 16 + nq;
                af[r] = *(const half8*)(Ab + (size_t)row * strideA + k0 + quad * 8);
            }
#pragma unroll
            for (int t = 0; t < NT; ++t) {
                const h16* wp = &Wt[(t * 16 + nq) * WT_STRIDE + quad * 8];
                half8 bf;
                *(uint2*)&bf = *(const uint2*)wp;
                *((uint2*)&bf + 1) = *(const uint2*)(wp + 4);
                acc[0][t] = __builtin_amdgcn_mfma_f32_16x16x32_f16(af[0], bf, acc[0][t], 0, 0, 0);
                acc[1][t] = __builtin_amdgcn_mfma_f32_16x16x32_f16(af[1], bf, acc[1][t], 0, 0, 0);
            }
        }
    }
    // epilogue: C layout col=lane&15, row=quad*4+reg
#pragma unroll
    for (int r = 0; r < 2; ++r) {
        int rowb = mrow + r * 16 + quad * 4;
#pragma unroll
        for (int t = 0; t < NT; ++t) {
            int col = t * 16 + nq;
            if (col >= HD) continue;
            float bj = bias[col];
#pragma unroll
            for (int g = 0; g < 4; ++g) {
                int row = rowb + g;
                if (row < n) {
                    float v = fmaxf(acc[r][t][g] + bj, 0.0f);
                    outF[(size_t)row * HD + col] = v;
                    if (out16) out16[(size_t)row * KPAD + col] = (h16)v;
                }
            }
        }
    }
}

// ---------- pooling: one wave per node ----------
__global__ void k_pool(const float* __restrict__ h, const int* __restrict__ batch,
                       float* __restrict__ psum, float* __restrict__ pmax,
                       float* __restrict__ cnt, int n) {
    int i = blockIdx.x * 4 + (threadIdx.x >> 6);
    int lane = threadIdx.x & 63;
    if (i >= n) return;
    int g = batch[i];
    if (lane == 0) atomicAdd(&cnt[g], 1.0f);
    const float* hr = h + (size_t)i * HD;
    for (int f = lane; f < HD; f += 64) {
        float v = hr[f];
        atomicAdd(&psum[g * HD + f], v);
        atomicMax((unsigned int*)&pmax[g * HD + f], __float_as_uint(v));  // v >= 0 post-ReLU
    }
}

// ---------- FC + log_softmax: one wave per graph ----------
__global__ void k_fc(const float* __restrict__ psum, const float* __restrict__ pmax,
                     const float* __restrict__ cnt, const float* __restrict__ fcw,
                     const float* __restrict__ fcb, float* __restrict__ out) {
    int g = blockIdx.x;
    int lane = threadIdx.x;
    float inv = 1.0f / fmaxf(cnt[g], 1.0f);
    float z0 = 0.0f, z1 = 0.0f;
    for (int j = lane; j < HD; j += 64) {
        float m = psum[g * HD + j] * inv;
        float M = pmax[g * HD + j];
        z0 += m * fcw[j * 2 + 0] + M * fcw[(HD + j) * 2 + 0];
        z1 += m * fcw[j * 2 + 1] + M * fcw[(HD + j) * 2 + 1];
    }
#pragma unroll
    for (int o = 32; o > 0; o >>= 1) {
        z0 += __shfl_down(z0, o);
        z1 += __shfl_down(z1, o);
    }
    if (lane == 0) {
        z0 += fcb[0];
        z1 += fcb[1];
        float m = fmaxf(z0, z1);
        float lse = m + logf(expf(z0 - m) + expf(z1 - m));
        out[g * 2 + 0] = z0 - lse;
        out[g * 2 + 1] = z1 - lse;
    }
}

extern "C" void kernel_launch(void* const* d_in, const int* in_sizes, int n_in,
                              void* d_out, int out_size, void* d_ws, size_t ws_size,
                              hipStream_t stream) {
    const float* x     = (const float*)d_in[0];
    const int*   edge  = (const int*)d_in[1];
    const int*   batch = (const int*)d_in[2];
    const float* lmax  = (const float*)d_in[3];
    const float* W1 = (const float*)d_in[4];  const float* b1 = (const float*)d_in[5];
    const float* W2 = (const float*)d_in[6];  const float* b2 = (const float*)d_in[7];
    const float* W3 = (const float*)d_in[8];  const float* b3 = (const float*)d_in[9];
    const float* W4 = (const float*)d_in[10]; const float* b4 = (const float*)d_in[11];
    const float* fcw = (const float*)d_in[12]; const float* fcb = (const float*)d_in[13];
    float* out = (float*)d_out;

    const int n = NN, E = NE;
    const int* src = edge;
    const int* dst = edge + E;

    // workspace layout (float units, each buffer 16B-aligned)
    float* ws = (float*)d_ws;
    size_t off = 0;
    auto alloc = [&](size_t nfloats) { float* p = ws + off; off += (nfloats + 3) & ~(size_t)3; return p; };
    float* dis   = alloc(NN);
    float* diag  = alloc(NN);
    float* wE    = alloc(NE);
    int*   cntd  = (int*)alloc(NN);
    int*   rowst = (int*)alloc(NN);
    int*   fill  = (int*)alloc(NN);
    int*   bsum  = (int*)alloc(SCAN_B);
    int*   csrs  = (int*)alloc(NE);
    float* csrw  = alloc(NE);
    float* cnt   = alloc(NG);
    float* psum  = alloc((size_t)NG * HD);
    float* pmax  = alloc((size_t)NG * HD);
    float* H     = alloc((size_t)MP * HD);        // f32 node features (in-place per layer)
    float* B     = alloc((size_t)MP * HD);        // f32 Tx1 scratch
    h16*   x16   = (h16*)alloc((size_t)MP * FIN / 2);   // fp16 x
    h16*   hi0   = (h16*)alloc((size_t)MP * KPAD / 2);  // fp16 Tx0 (in-place per layer)
    h16*   hi1   = (h16*)alloc((size_t)MP * KPAD / 2);  // fp16 Tx1
    h16*   hi2   = (h16*)alloc((size_t)MP * KPAD / 2);  // fp16 Tx2

    dim3 blk(256);
    int gE = (E + 255) / 256;
    int gN = (n + 255) / 256;
    int gScan = (n + SCAN_B - 1) / SCAN_B;
    int gN4 = (n + 3) / 4;
    int gGemm = (NN + 127) / 128;   // 391

    // --- zero pads/garbage rows of fp16 tile buffers (ws re-poisoned every call) ---
    hipMemsetAsync(hi0, 0, (size_t)MP * KPAD * 2, stream);
    hipMemsetAsync(hi1, 0, (size_t)MP * KPAD * 2, stream);
    hipMemsetAsync(hi2, 0, (size_t)MP * KPAD * 2, stream);

    // --- normalization + CSR build ---
    hipMemsetAsync(dis, 0, (size_t)NN * 4, stream);
    hipMemsetAsync(cntd, 0, (size_t)NN * 4, stream);
    hipMemsetAsync(fill, 0, (size_t)NN * 4, stream);
    k_deg<<<gE, blk, 0, stream>>>(src, dst, dis, cntd, E);
    k_node_prep<<<gN, blk, 0, stream>>>(dis, batch, lmax, diag, n);
    k_edge_w<<<gE, blk, 0, stream>>>(src, dst, batch, lmax, dis, wE, E);
    k_scan1<<<gScan, blk, 0, stream>>>(cntd, rowst, bsum, n);
    k_scan2<<<1, blk, 0, stream>>>(bsum, gScan);
    k_scan3<<<gScan, blk, 0, stream>>>(rowst, bsum, n);
    k_fillcsr<<<gE, blk, 0, stream>>>(src, dst, wE, rowst, fill, csrs, csrw, E);
    k_split<<<(NN * FIN + 255) / 256, blk, 0, stream>>>(x, x16, NN * FIN);

    // --- 4 Chebyshev layers ---
    const float* Wl[4] = {W1, W2, W3, W4};
    const float* bl[4] = {b1, b2, b3, b4};
    for (int l = 0; l < 4; l++) {
        int fin = (l == 0) ? FIN : HD;
        int s16 = (l == 0) ? FIN : KPAD;
        const float* h = (l == 0) ? x : H;
        const h16* a0 = (l == 0) ? x16 : hi0;
        // Tx1 = prop(h)  -> B (f32) + hi1 (fp16)
        k_gather<<<gN4, blk, 0, stream>>>(rowst, cntd, csrs, csrw, diag, h, h, B, hi1, s16, n, fin, 0);
        // Tx2 = 2*prop(Tx1) - h  -> hi2 (fp16)
        k_gather<<<gN4, blk, 0, stream>>>(rowst, cntd, csrs, csrw, diag, B, h, nullptr, hi2, s16, n, fin, 1);
        // out = relu([Tx0|Tx1|Tx2] @ W + b) -> H (f32) + hi0 (fp16, next layer's Tx0)
        k_gemm16<<<gGemm, blk, 0, stream>>>(a0, hi1, hi2, s16, fin, Wl[l], bl[l],
                                            H, (l < 3) ? hi0 : nullptr, n);
    }

    // --- pooling + FC head ---
    hipMemsetAsync(psum, 0, (size_t)NG * HD * 4, stream);
    hipMemsetAsync(pmax, 0, (size_t)NG * HD * 4, stream);
    hipMemsetAsync(cnt, 0, (size_t)NG * 4, stream);
    k_pool<<<gN4, blk, 0, stream>>>(H, batch, psum, pmax, cnt, n);
    k_fc<<<NG, dim3(64), 0, stream>>>(psum, pmax, cnt, fcw, fcb, out);
}

// Round 4
// 1309.171 us; speedup vs baseline: 4.1985x; 1.5712x over previous
//
#include <hip/hip_runtime.h>
#include <math.h>

#define NN 50000
#define MP 50048          // NN padded to multiple of 64 (16 rows x 4 waves)
#define NE 800000
#define FIN 64
#define HD 200
#define NG 256
#define SCAN_B 256
#define KPAD 224          // HD padded to multiple of 32 for MFMA K-steps
#define NT 13             // 13 * 16 = 208 >= 200 output col tiles

typedef _Float16 h16;
typedef __attribute__((ext_vector_type(8))) _Float16 half8;
typedef __attribute__((ext_vector_type(4))) float float4v;

// ---------- setup: src out-degree (float) + dst in-degree (int, for CSR) ----------
__global__ void k_deg(const int* __restrict__ src, const int* __restrict__ dst,
                      float* __restrict__ deg, int* __restrict__ cnt_dst, int E) {
    int e = blockIdx.x * blockDim.x + threadIdx.x;
    if (e < E) {
        atomicAdd(&deg[src[e]], 1.0f);
        atomicAdd(&cnt_dst[dst[e]], 1);
    }
}

__global__ void k_node_prep(float* __restrict__ degdis, const int* __restrict__ batch,
                            const float* __restrict__ lmax, float* __restrict__ diag, int n) {
    int i = blockIdx.x * blockDim.x + threadIdx.x;
    if (i < n) {
        float d = degdis[i];
        degdis[i] = (d > 0.f) ? (1.0f / sqrtf(fmaxf(d, 1.0f))) : 0.0f;   // dis
        diag[i] = 2.0f / lmax[batch[i]] - 1.0f;
    }
}

__global__ void k_edge_w(const int* __restrict__ src, const int* __restrict__ dst,
                         const int* __restrict__ batch, const float* __restrict__ lmax,
                         const float* __restrict__ dis, float* __restrict__ w, int E) {
    int e = blockIdx.x * blockDim.x + threadIdx.x;
    if (e < E) {
        int s = src[e], d = dst[e];
        w[e] = -dis[s] * dis[d] * (2.0f / lmax[batch[s]]);
    }
}

// ---------- exclusive scan over cnt_dst ----------
__global__ void k_scan1(const int* __restrict__ cnt, int* __restrict__ excl,
                        int* __restrict__ bsum, int n) {
    __shared__ int sh[SCAN_B];
    int tid = threadIdx.x;
    int i = blockIdx.x * SCAN_B + tid;
    int v = (i < n) ? cnt[i] : 0;
    sh[tid] = v;
    __syncthreads();
    for (int off = 1; off < SCAN_B; off <<= 1) {
        int t = (tid >= off) ? sh[tid - off] : 0;
        __syncthreads();
        sh[tid] += t;
        __syncthreads();
    }
    if (i < n) excl[i] = sh[tid] - v;
    if (tid == SCAN_B - 1) bsum[blockIdx.x] = sh[tid];
}

__global__ void k_scan2(int* __restrict__ bsum, int nb) {
    __shared__ int sh[SCAN_B];
    int tid = threadIdx.x;
    int v = (tid < nb) ? bsum[tid] : 0;
    sh[tid] = v;
    __syncthreads();
    for (int off = 1; off < SCAN_B; off <<= 1) {
        int t = (tid >= off) ? sh[tid - off] : 0;
        __syncthreads();
        sh[tid] += t;
        __syncthreads();
    }
    if (tid < nb) bsum[tid] = sh[tid] - v;   // exclusive
}

__global__ void k_scan3(int* __restrict__ excl, const int* __restrict__ bsum, int n) {
    int i = blockIdx.x * SCAN_B + threadIdx.x;
    if (i < n) excl[i] += bsum[blockIdx.x];
}

// ---------- permute edges into CSR-by-dst order ----------
__global__ void k_fillcsr(const int* __restrict__ src, const int* __restrict__ dst,
                          const float* __restrict__ w, const int* __restrict__ rowstart,
                          int* __restrict__ fill, int* __restrict__ csr_src,
                          float* __restrict__ csr_w, int E) {
    int e = blockIdx.x * blockDim.x + threadIdx.x;
    if (e < E) {
        int d = dst[e];
        int pos = rowstart[d] + atomicAdd(&fill[d], 1);
        csr_src[pos] = src[e];
        csr_w[pos] = w[e];
    }
}

// ---------- fp32 -> fp16 split for x ----------
__global__ void k_split(const float* __restrict__ x, h16* __restrict__ x16, int total) {
    int i = blockIdx.x * blockDim.x + threadIdx.x;
    if (i < total) x16[i] = (h16)x[i];
}

// ---------- W pre-transpose: f32 [3][fin][HD] -> fp16 [seg][ks][208][32] ----------
__global__ void k_wprep(const float* __restrict__ W, h16* __restrict__ out,
                        int fin, int ksteps, int total) {
    int idx = blockIdx.x * blockDim.x + threadIdx.x;
    if (idx >= total) return;
    int kk = idx & 31;
    int r = idx >> 5;
    int nn = r % 208;
    int r2 = r / 208;
    int ks = r2 % ksteps;
    int seg = r2 / ksteps;
    int k = ks * 32 + kk;
    out[idx] = (nn < HD && k < fin) ? (h16)W[((size_t)seg * fin + k) * HD + nn] : (h16)0.f;
}

// ---------- propagation (gather, fp16 in / fp16 out): one wave per node ----------
// mode 0: v = gath + diag*hin
// mode 1: v = 2*(gath + diag*hin) - hin0
__global__ __launch_bounds__(256) void k_gather(
    const int* __restrict__ rowstart, const int* __restrict__ rowcnt,
    const int* __restrict__ csr_src, const float* __restrict__ csr_w,
    const float* __restrict__ diag, const h16* __restrict__ hin16,
    const h16* __restrict__ h016, h16* __restrict__ hout16,
    int s16, int n, int mode) {
    int i = blockIdx.x * 4 + (threadIdx.x >> 6);
    if (i >= n) return;
    int lane = threadIdx.x & 63;
    int c0 = lane * 4;
    if (c0 >= s16) return;   // inactive lanes (layer-0 stride 64)
    int start = rowstart[i], cnt = rowcnt[i];
    float a0 = 0.f, a1 = 0.f, a2 = 0.f, a3 = 0.f;
    union U { uint2 u; h16 h[4]; };
    int k = 0;
    for (; k + 1 < cnt; k += 2) {
        int s0 = csr_src[start + k], s1 = csr_src[start + k + 1];
        float w0 = csr_w[start + k], w1 = csr_w[start + k + 1];
        U p0, p1;
        p0.u = *(const uint2*)(hin16 + (size_t)s0 * s16 + c0);
        p1.u = *(const uint2*)(hin16 + (size_t)s1 * s16 + c0);
        a0 += w0 * (float)p0.h[0] + w1 * (float)p1.h[0];
        a1 += w0 * (float)p0.h[1] + w1 * (float)p1.h[1];
        a2 += w0 * (float)p0.h[2] + w1 * (float)p1.h[2];
        a3 += w0 * (float)p0.h[3] + w1 * (float)p1.h[3];
    }
    if (k < cnt) {
        int s0 = csr_src[start + k];
        float w0 = csr_w[start + k];
        U p0;
        p0.u = *(const uint2*)(hin16 + (size_t)s0 * s16 + c0);
        a0 += w0 * (float)p0.h[0];
        a1 += w0 * (float)p0.h[1];
        a2 += w0 * (float)p0.h[2];
        a3 += w0 * (float)p0.h[3];
    }
    float dg = diag[i];
    U hs; hs.u = *(const uint2*)(hin16 + (size_t)i * s16 + c0);
    float v0 = a0 + dg * (float)hs.h[0];
    float v1 = a1 + dg * (float)hs.h[1];
    float v2 = a2 + dg * (float)hs.h[2];
    float v3 = a3 + dg * (float)hs.h[3];
    if (mode == 1) {
        U h0; h0.u = *(const uint2*)(h016 + (size_t)i * s16 + c0);
        v0 = 2.f * v0 - (float)h0.h[0];
        v1 = 2.f * v1 - (float)h0.h[1];
        v2 = 2.f * v2 - (float)h0.h[2];
        v3 = 2.f * v3 - (float)h0.h[3];
    }
    U o;
    o.h[0] = (h16)v0; o.h[1] = (h16)v1; o.h[2] = (h16)v2; o.h[3] = (h16)v3;
    *(uint2*)(hout16 + (size_t)i * s16 + c0) = o.u;
}

// ---------- MFMA fp16 GEMM, barrier-free: out = relu([A0|A1|A2] @ W + b) ----------
// Wt16: fp16 [seg][ks][208][32] (B-fragment-ready, L2-resident).
// Each wave: 16 rows x 208 cols.
__global__ __launch_bounds__(256) void k_gemm16(
    const h16* __restrict__ A0, const h16* __restrict__ A1, const h16* __restrict__ A2,
    int strideA, int ksteps,
    const h16* __restrict__ Wt, const float* __restrict__ bias,
    float* __restrict__ outF, h16* __restrict__ out16, int n) {
    int tid = threadIdx.x;
    int wave = tid >> 6, lane = tid & 63;
    int nq = lane & 15, quad = lane >> 4;
    int row0 = (blockIdx.x * 4 + wave) * 16;
    const h16* Aseg[3] = {A0, A1, A2};

    float4v acc[NT];
#pragma unroll
    for (int t = 0; t < NT; t++) acc[t] = (float4v)0.f;

    int arow = row0 + nq;
    for (int seg = 0; seg < 3; ++seg) {
        const h16* Ab = Aseg[seg] + (size_t)arow * strideA + quad * 8;
        const h16* Bb = Wt + (size_t)seg * ksteps * 208 * 32 + (size_t)nq * 32 + quad * 8;
        for (int ks = 0; ks < ksteps; ++ks) {
            half8 af = *(const half8*)(Ab + ks * 32);
            const h16* Bk = Bb + (size_t)ks * 208 * 32;
#pragma unroll
            for (int t = 0; t < NT; ++t) {
                half8 bf = *(const half8*)(Bk + t * 16 * 32);
                acc[t] = __builtin_amdgcn_mfma_f32_16x16x32_f16(af, bf, acc[t], 0, 0, 0);
            }
        }
    }
    // epilogue: C layout col=lane&15, row=quad*4+reg
    int rowb = row0 + quad * 4;
#pragma unroll
    for (int t = 0; t < NT; ++t) {
        int col = t * 16 + nq;
        if (col >= HD) continue;
        float bj = bias[col];
#pragma unroll
        for (int g = 0; g < 4; ++g) {
            int row = rowb + g;
            if (row < n) {
                float v = fmaxf(acc[t][g] + bj, 0.0f);
                if (outF)  outF[(size_t)row * HD + col] = v;
                if (out16) out16[(size_t)row * KPAD + col] = (h16)v;
            }
        }
    }
}

// ---------- pooling: one wave per node ----------
__global__ void k_pool(const float* __restrict__ h, const int* __restrict__ batch,
                       float* __restrict__ psum, float* __restrict__ pmax,
                       float* __restrict__ cnt, int n) {
    int i = blockIdx.x * 4 + (threadIdx.x >> 6);
    int lane = threadIdx.x & 63;
    if (i >= n) return;
    int g = batch[i];
    if (lane == 0) atomicAdd(&cnt[g], 1.0f);
    const float* hr = h + (size_t)i * HD;
    for (int f = lane; f < HD; f += 64) {
        float v = hr[f];
        atomicAdd(&psum[g * HD + f], v);
        atomicMax((unsigned int*)&pmax[g * HD + f], __float_as_uint(v));  // v >= 0 post-ReLU
    }
}

// ---------- FC + log_softmax: one wave per graph ----------
__global__ void k_fc(const float* __restrict__ psum, const float* __restrict__ pmax,
                     const float* __restrict__ cnt, const float* __restrict__ fcw,
                     const float* __restrict__ fcb, float* __restrict__ out) {
    int g = blockIdx.x;
    int lane = threadIdx.x;
    float inv = 1.0f / fmaxf(cnt[g], 1.0f);
    float z0 = 0.0f, z1 = 0.0f;
    for (int j = lane; j < HD; j += 64) {
        float m = psum[g * HD + j] * inv;
        float M = pmax[g * HD + j];
        z0 += m * fcw[j * 2 + 0] + M * fcw[(HD + j) * 2 + 0];
        z1 += m * fcw[j * 2 + 1] + M * fcw[(HD + j) * 2 + 1];
    }
#pragma unroll
    for (int o = 32; o > 0; o >>= 1) {
        z0 += __shfl_down(z0, o);
        z1 += __shfl_down(z1, o);
    }
    if (lane == 0) {
        z0 += fcb[0];
        z1 += fcb[1];
        float m = fmaxf(z0, z1);
        float lse = m + logf(expf(z0 - m) + expf(z1 - m));
        out[g * 2 + 0] = z0 - lse;
        out[g * 2 + 1] = z1 - lse;
    }
}

extern "C" void kernel_launch(void* const* d_in, const int* in_sizes, int n_in,
                              void* d_out, int out_size, void* d_ws, size_t ws_size,
                              hipStream_t stream) {
    const float* x     = (const float*)d_in[0];
    const int*   edge  = (const int*)d_in[1];
    const int*   batch = (const int*)d_in[2];
    const float* lmax  = (const float*)d_in[3];
    const float* W1 = (const float*)d_in[4];  const float* b1 = (const float*)d_in[5];
    const float* W2 = (const float*)d_in[6];  const float* b2 = (const float*)d_in[7];
    const float* W3 = (const float*)d_in[8];  const float* b3 = (const float*)d_in[9];
    const float* W4 = (const float*)d_in[10]; const float* b4 = (const float*)d_in[11];
    const float* fcw = (const float*)d_in[12]; const float* fcb = (const float*)d_in[13];
    float* out = (float*)d_out;

    const int n = NN, E = NE;
    const int* src = edge;
    const int* dst = edge + E;

    // workspace layout (float units, each buffer 16B-aligned)
    float* ws = (float*)d_ws;
    size_t off = 0;
    auto alloc = [&](size_t nfloats) { float* p = ws + off; off += (nfloats + 3) & ~(size_t)3; return p; };
    float* dis   = alloc(NN);
    float* diag  = alloc(NN);
    float* wE    = alloc(NE);
    int*   cntd  = (int*)alloc(NN);
    int*   rowst = (int*)alloc(NN);
    int*   fill  = (int*)alloc(NN);
    int*   bsum  = (int*)alloc(SCAN_B);
    int*   csrs  = (int*)alloc(NE);
    float* csrw  = alloc(NE);
    float* cnt   = alloc(NG);
    float* psum  = alloc((size_t)NG * HD);
    float* pmax  = alloc((size_t)NG * HD);
    float* H     = alloc((size_t)MP * HD);                // f32 final-layer features (pool)
    h16*   x16   = (h16*)alloc((size_t)MP * FIN / 2);     // fp16 x
    h16*   hi0   = (h16*)alloc((size_t)MP * KPAD / 2);    // fp16 Tx0 (in-place per layer)
    h16*   hi1   = (h16*)alloc((size_t)MP * KPAD / 2);    // fp16 Tx1
    h16*   hi2   = (h16*)alloc((size_t)MP * KPAD / 2);    // fp16 Tx2
    const int WSZ0 = 3 * 2 * 208 * 32;                    // layer 0 (fin=64, ksteps=2)
    const int WSZ  = 3 * 7 * 208 * 32;                    // layers 1-3 (fin=200, ksteps=7)
    h16* wt0 = (h16*)alloc(WSZ0 / 2);
    h16* wt1 = (h16*)alloc(WSZ / 2);
    h16* wt2 = (h16*)alloc(WSZ / 2);
    h16* wt3 = (h16*)alloc(WSZ / 2);

    dim3 blk(256);
    int gE = (E + 255) / 256;
    int gN = (n + 255) / 256;
    int gScan = (n + SCAN_B - 1) / SCAN_B;
    int gN4 = (n + 3) / 4;
    int gGemm = MP / 64;    // 782 blocks, 4 waves x 16 rows

    // --- W pre-transpose (L2-resident fp16 fragments) + x fp16 ---
    k_wprep<<<(WSZ0 + 255) / 256, blk, 0, stream>>>(W1, wt0, FIN, 2, WSZ0);
    k_wprep<<<(WSZ + 255) / 256, blk, 0, stream>>>(W2, wt1, HD, 7, WSZ);
    k_wprep<<<(WSZ + 255) / 256, blk, 0, stream>>>(W3, wt2, HD, 7, WSZ);
    k_wprep<<<(WSZ + 255) / 256, blk, 0, stream>>>(W4, wt3, HD, 7, WSZ);
    k_split<<<(NN * FIN + 255) / 256, blk, 0, stream>>>(x, x16, NN * FIN);
    // hi0 pads (cols 200..223) must be zero: gemm only writes cols<200
    hipMemsetAsync(hi0, 0, (size_t)MP * KPAD * 2, stream);

    // --- normalization + CSR build ---
    hipMemsetAsync(dis, 0, (size_t)NN * 4, stream);
    hipMemsetAsync(cntd, 0, (size_t)NN * 4, stream);
    hipMemsetAsync(fill, 0, (size_t)NN * 4, stream);
    k_deg<<<gE, blk, 0, stream>>>(src, dst, dis, cntd, E);
    k_node_prep<<<gN, blk, 0, stream>>>(dis, batch, lmax, diag, n);
    k_edge_w<<<gE, blk, 0, stream>>>(src, dst, batch, lmax, dis, wE, E);
    k_scan1<<<gScan, blk, 0, stream>>>(cntd, rowst, bsum, n);
    k_scan2<<<1, blk, 0, stream>>>(bsum, gScan);
    k_scan3<<<gScan, blk, 0, stream>>>(rowst, bsum, n);
    k_fillcsr<<<gE, blk, 0, stream>>>(src, dst, wE, rowst, fill, csrs, csrw, E);

    // --- 4 Chebyshev layers ---
    const h16* wt[4] = {wt0, wt1, wt2, wt3};
    const float* bl[4] = {b1, b2, b3, b4};
    for (int l = 0; l < 4; l++) {
        int s16 = (l == 0) ? FIN : KPAD;
        int ksteps = (l == 0) ? 2 : 7;
        const h16* a0 = (l == 0) ? x16 : hi0;
        // Tx1 = prop(Tx0) -> hi1
        k_gather<<<gN4, blk, 0, stream>>>(rowst, cntd, csrs, csrw, diag, a0, a0, hi1, s16, n, 0);
        // Tx2 = 2*prop(Tx1) - Tx0 -> hi2
        k_gather<<<gN4, blk, 0, stream>>>(rowst, cntd, csrs, csrw, diag, hi1, a0, hi2, s16, n, 1);
        // out = relu([Tx0|Tx1|Tx2] @ W + b)
        k_gemm16<<<gGemm, blk, 0, stream>>>(a0, hi1, hi2, s16, ksteps, wt[l], bl[l],
                                            (l == 3) ? H : nullptr,
                                            (l < 3) ? hi0 : nullptr, n);
    }

    // --- pooling + FC head ---
    hipMemsetAsync(psum, 0, (size_t)NG * HD * 4, stream);
    hipMemsetAsync(pmax, 0, (size_t)NG * HD * 4, stream);
    hipMemsetAsync(cnt, 0, (size_t)NG * 4, stream);
    k_pool<<<gN4, blk, 0, stream>>>(H, batch, psum, pmax, cnt, n);
    k_fc<<<NG, dim3(64), 0, stream>>>(psum, pmax, cnt, fcw, fcb, out);
}

// Round 5
// 1184.659 us; speedup vs baseline: 4.6398x; 1.1051x over previous
//
#include <hip/hip_runtime.h>
#include <math.h>

#define NN 50000
#define MP 50048          // NN padded to multiple of 64
#define NE 800000
#define FIN 64
#define HD 200
#define NG 256
#define SCAN_B 256
#define KPAD 224          // HD padded to multiple of 32 for MFMA K-steps
#define NT 13             // 13 * 16 = 208 >= 200 output col tiles

typedef _Float16 h16;
typedef __attribute__((ext_vector_type(8))) _Float16 half8;
typedef __attribute__((ext_vector_type(4))) float float4v;

// ---------- setup: src out-degree (float) + dst in-degree (int, for CSR) ----------
__global__ void k_deg(const int* __restrict__ src, const int* __restrict__ dst,
                      float* __restrict__ deg, int* __restrict__ cnt_dst, int E) {
    int e = blockIdx.x * blockDim.x + threadIdx.x;
    if (e < E) {
        atomicAdd(&deg[src[e]], 1.0f);
        atomicAdd(&cnt_dst[dst[e]], 1);
    }
}

__global__ void k_node_prep(float* __restrict__ degdis, const int* __restrict__ batch,
                            const float* __restrict__ lmax, float* __restrict__ diag, int n) {
    int i = blockIdx.x * blockDim.x + threadIdx.x;
    if (i < n) {
        float d = degdis[i];
        degdis[i] = (d > 0.f) ? (1.0f / sqrtf(fmaxf(d, 1.0f))) : 0.0f;   // dis
        diag[i] = 2.0f / lmax[batch[i]] - 1.0f;
    }
}

__global__ void k_edge_w(const int* __restrict__ src, const int* __restrict__ dst,
                         const int* __restrict__ batch, const float* __restrict__ lmax,
                         const float* __restrict__ dis, float* __restrict__ w, int E) {
    int e = blockIdx.x * blockDim.x + threadIdx.x;
    if (e < E) {
        int s = src[e], d = dst[e];
        w[e] = -dis[s] * dis[d] * (2.0f / lmax[batch[s]]);
    }
}

// ---------- exclusive scan over cnt_dst ----------
__global__ void k_scan1(const int* __restrict__ cnt, int* __restrict__ excl,
                        int* __restrict__ bsum, int n) {
    __shared__ int sh[SCAN_B];
    int tid = threadIdx.x;
    int i = blockIdx.x * SCAN_B + tid;
    int v = (i < n) ? cnt[i] : 0;
    sh[tid] = v;
    __syncthreads();
    for (int off = 1; off < SCAN_B; off <<= 1) {
        int t = (tid >= off) ? sh[tid - off] : 0;
        __syncthreads();
        sh[tid] += t;
        __syncthreads();
    }
    if (i < n) excl[i] = sh[tid] - v;
    if (tid == SCAN_B - 1) bsum[blockIdx.x] = sh[tid];
}

__global__ void k_scan2(int* __restrict__ bsum, int nb) {
    __shared__ int sh[SCAN_B];
    int tid = threadIdx.x;
    int v = (tid < nb) ? bsum[tid] : 0;
    sh[tid] = v;
    __syncthreads();
    for (int off = 1; off < SCAN_B; off <<= 1) {
        int t = (tid >= off) ? sh[tid - off] : 0;
        __syncthreads();
        sh[tid] += t;
        __syncthreads();
    }
    if (tid < nb) bsum[tid] = sh[tid] - v;   // exclusive
}

__global__ void k_scan3(int* __restrict__ excl, const int* __restrict__ bsum, int n) {
    int i = blockIdx.x * SCAN_B + threadIdx.x;
    if (i < n) excl[i] += bsum[blockIdx.x];
}

// ---------- permute edges into CSR-by-dst order ----------
__global__ void k_fillcsr(const int* __restrict__ src, const int* __restrict__ dst,
                          const float* __restrict__ w, const int* __restrict__ rowstart,
                          int* __restrict__ fill, int* __restrict__ csr_src,
                          float* __restrict__ csr_w, int E) {
    int e = blockIdx.x * blockDim.x + threadIdx.x;
    if (e < E) {
        int d = dst[e];
        int pos = rowstart[d] + atomicAdd(&fill[d], 1);
        csr_src[pos] = src[e];
        csr_w[pos] = w[e];
    }
}

// ---------- fp32 -> fp16 split for x ----------
__global__ void k_split(const float* __restrict__ x, h16* __restrict__ x16, int total) {
    int i = blockIdx.x * blockDim.x + threadIdx.x;
    if (i < total) x16[i] = (h16)x[i];
}

// ---------- W pre-transpose: f32 [3][fin][HD] -> fp16 [seg][ks][208][32] ----------
__global__ void k_wprep(const float* __restrict__ W, h16* __restrict__ out,
                        int fin, int ksteps, int total) {
    int idx = blockIdx.x * blockDim.x + threadIdx.x;
    if (idx >= total) return;
    int kk = idx & 31;
    int r = idx >> 5;
    int nn = r % 208;
    int r2 = r / 208;
    int ks = r2 % ksteps;
    int seg = r2 / ksteps;
    int k = ks * 32 + kk;
    out[idx] = (nn < HD && k < fin) ? (h16)W[((size_t)seg * fin + k) * HD + nn] : (h16)0.f;
}

// ---------- graph boundaries (batch is sorted) ----------
__global__ void k_bounds(const int* __restrict__ batch, int* __restrict__ gstart, int n) {
    int g = blockIdx.x * blockDim.x + threadIdx.x;
    if (g > NG) return;
    if (g == NG) { gstart[NG] = n; return; }
    int lo = 0, hi = n;
    while (lo < hi) {
        int mid = (lo + hi) >> 1;
        if (batch[mid] < g) lo = mid + 1; else hi = mid;
    }
    gstart[g] = lo;
}

// ---------- propagation (gather, fp16, column-chunked for L2 locality) ----------
// 16-lane group per node, chunk = blockIdx.y covers CW halfs starting at CW*chunk.
// mode 0: v = gath + diag*hin        mode 1: v = 2*(gath + diag*hin) - hin0
__global__ __launch_bounds__(256) void k_gather(
    const int* __restrict__ rowstart, const int* __restrict__ rowcnt,
    const int* __restrict__ csr_src, const float* __restrict__ csr_w,
    const float* __restrict__ diag, const h16* __restrict__ hin16,
    const h16* __restrict__ h016, h16* __restrict__ hout16,
    int s16, int CW, int n, int mode) {
    int i = blockIdx.x * 16 + (threadIdx.x >> 4);
    if (i >= n) return;
    int glane = threadIdx.x & 15;
    if (glane * 4 >= CW) return;                    // inactive lanes (CW=56 -> 14/16)
    int c0 = blockIdx.y * CW + glane * 4;
    int start = rowstart[i], cnt = rowcnt[i];
    float a0 = 0.f, a1 = 0.f, a2 = 0.f, a3 = 0.f;
    union U { uint2 u; h16 h[4]; };
    int k = 0;
    for (; k + 1 < cnt; k += 2) {
        int s0 = csr_src[start + k], s1 = csr_src[start + k + 1];
        float w0 = csr_w[start + k], w1 = csr_w[start + k + 1];
        U p0, p1;
        p0.u = *(const uint2*)(hin16 + (size_t)s0 * s16 + c0);
        p1.u = *(const uint2*)(hin16 + (size_t)s1 * s16 + c0);
        a0 += w0 * (float)p0.h[0] + w1 * (float)p1.h[0];
        a1 += w0 * (float)p0.h[1] + w1 * (float)p1.h[1];
        a2 += w0 * (float)p0.h[2] + w1 * (float)p1.h[2];
        a3 += w0 * (float)p0.h[3] + w1 * (float)p1.h[3];
    }
    if (k < cnt) {
        int s0 = csr_src[start + k];
        float w0 = csr_w[start + k];
        U p0;
        p0.u = *(const uint2*)(hin16 + (size_t)s0 * s16 + c0);
        a0 += w0 * (float)p0.h[0];
        a1 += w0 * (float)p0.h[1];
        a2 += w0 * (float)p0.h[2];
        a3 += w0 * (float)p0.h[3];
    }
    float dg = diag[i];
    U hs; hs.u = *(const uint2*)(hin16 + (size_t)i * s16 + c0);
    float v0 = a0 + dg * (float)hs.h[0];
    float v1 = a1 + dg * (float)hs.h[1];
    float v2 = a2 + dg * (float)hs.h[2];
    float v3 = a3 + dg * (float)hs.h[3];
    if (mode == 1) {
        U h0; h0.u = *(const uint2*)(h016 + (size_t)i * s16 + c0);
        v0 = 2.f * v0 - (float)h0.h[0];
        v1 = 2.f * v1 - (float)h0.h[1];
        v2 = 2.f * v2 - (float)h0.h[2];
        v3 = 2.f * v3 - (float)h0.h[3];
    }
    U o;
    o.h[0] = (h16)v0; o.h[1] = (h16)v1; o.h[2] = (h16)v2; o.h[3] = (h16)v3;
    *(uint2*)(hout16 + (size_t)i * s16 + c0) = o.u;
}

// ---------- MFMA fp16 GEMM, barrier-free: out = relu([A0|A1|A2] @ W + b) ----------
__global__ __launch_bounds__(256) void k_gemm16(
    const h16* __restrict__ A0, const h16* __restrict__ A1, const h16* __restrict__ A2,
    int strideA, int ksteps,
    const h16* __restrict__ Wt, const float* __restrict__ bias,
    float* __restrict__ outF, h16* __restrict__ out16, int n) {
    int tid = threadIdx.x;
    int wave = tid >> 6, lane = tid & 63;
    int nq = lane & 15, quad = lane >> 4;
    int row0 = (blockIdx.x * 4 + wave) * 16;
    const h16* Aseg[3] = {A0, A1, A2};

    float4v acc[NT];
#pragma unroll
    for (int t = 0; t < NT; t++) acc[t] = (float4v)0.f;

    int arow = row0 + nq;
    for (int seg = 0; seg < 3; ++seg) {
        const h16* Ab = Aseg[seg] + (size_t)arow * strideA + quad * 8;
        const h16* Bb = Wt + (size_t)seg * ksteps * 208 * 32 + (size_t)nq * 32 + quad * 8;
        for (int ks = 0; ks < ksteps; ++ks) {
            half8 af = *(const half8*)(Ab + ks * 32);
            const h16* Bk = Bb + (size_t)ks * 208 * 32;
#pragma unroll
            for (int t = 0; t < NT; ++t) {
                half8 bf = *(const half8*)(Bk + t * 16 * 32);
                acc[t] = __builtin_amdgcn_mfma_f32_16x16x32_f16(af, bf, acc[t], 0, 0, 0);
            }
        }
    }
    int rowb = row0 + quad * 4;
#pragma unroll
    for (int t = 0; t < NT; ++t) {
        int col = t * 16 + nq;
        if (col >= HD) continue;
        float bj = bias[col];
#pragma unroll
        for (int g = 0; g < 4; ++g) {
            int row = rowb + g;
            if (row < n) {
                float v = fmaxf(acc[t][g] + bj, 0.0f);
                if (outF)  outF[(size_t)row * HD + col] = v;
                if (out16) out16[(size_t)row * KPAD + col] = (h16)v;
            }
        }
    }
}

// ---------- fused segmented pool (mean+max) + FC + log_softmax: one block per graph ----------
__global__ __launch_bounds__(256) void k_pool_fc(
    const float* __restrict__ Hf, const int* __restrict__ gstart,
    const float* __restrict__ fcw, const float* __restrict__ fcb,
    float* __restrict__ out) {
    __shared__ float red[8];
    int g = blockIdx.x;
    int j = threadIdx.x;
    int i0 = gstart[g], i1 = gstart[g + 1];
    float s0 = 0.f, s1 = 0.f, s2 = 0.f, s3 = 0.f, mx = 0.f;   // post-ReLU: max >= 0
    if (j < HD) {
        int i = i0;
        for (; i + 3 < i1; i += 4) {
            float v0 = Hf[(size_t)i * HD + j];
            float v1 = Hf[(size_t)(i + 1) * HD + j];
            float v2 = Hf[(size_t)(i + 2) * HD + j];
            float v3 = Hf[(size_t)(i + 3) * HD + j];
            s0 += v0; s1 += v1; s2 += v2; s3 += v3;
            mx = fmaxf(mx, fmaxf(fmaxf(v0, v1), fmaxf(v2, v3)));
        }
        for (; i < i1; ++i) {
            float v = Hf[(size_t)i * HD + j];
            s0 += v; mx = fmaxf(mx, v);
        }
    }
    float cntf = (float)(i1 - i0);
    float mean = (s0 + s1 + s2 + s3) / fmaxf(cntf, 1.f);
    float p0 = 0.f, p1 = 0.f;
    if (j < HD) {
        p0 = mean * fcw[2 * j]     + mx * fcw[2 * (HD + j)];
        p1 = mean * fcw[2 * j + 1] + mx * fcw[2 * (HD + j) + 1];
    }
#pragma unroll
    for (int o = 32; o > 0; o >>= 1) {
        p0 += __shfl_down(p0, o);
        p1 += __shfl_down(p1, o);
    }
    int wave = j >> 6, lane = j & 63;
    if (lane == 0) { red[wave * 2] = p0; red[wave * 2 + 1] = p1; }
    __syncthreads();
    if (j == 0) {
        float z0 = red[0] + red[2] + red[4] + red[6] + fcb[0];
        float z1 = red[1] + red[3] + red[5] + red[7] + fcb[1];
        float m = fmaxf(z0, z1);
        float lse = m + logf(expf(z0 - m) + expf(z1 - m));
        out[g * 2 + 0] = z0 - lse;
        out[g * 2 + 1] = z1 - lse;
    }
}

extern "C" void kernel_launch(void* const* d_in, const int* in_sizes, int n_in,
                              void* d_out, int out_size, void* d_ws, size_t ws_size,
                              hipStream_t stream) {
    const float* x     = (const float*)d_in[0];
    const int*   edge  = (const int*)d_in[1];
    const int*   batch = (const int*)d_in[2];
    const float* lmax  = (const float*)d_in[3];
    const float* W1 = (const float*)d_in[4];  const float* b1 = (const float*)d_in[5];
    const float* W2 = (const float*)d_in[6];  const float* b2 = (const float*)d_in[7];
    const float* W3 = (const float*)d_in[8];  const float* b3 = (const float*)d_in[9];
    const float* W4 = (const float*)d_in[10]; const float* b4 = (const float*)d_in[11];
    const float* fcw = (const float*)d_in[12]; const float* fcb = (const float*)d_in[13];
    float* out = (float*)d_out;

    const int n = NN, E = NE;
    const int* src = edge;
    const int* dst = edge + E;

    // workspace layout (float units, each buffer 16B-aligned)
    float* ws = (float*)d_ws;
    size_t off = 0;
    auto alloc = [&](size_t nfloats) { float* p = ws + off; off += (nfloats + 3) & ~(size_t)3; return p; };
    float* dis    = alloc(NN);
    float* diag   = alloc(NN);
    float* wE     = alloc(NE);
    int*   cntd   = (int*)alloc(NN);
    int*   rowst  = (int*)alloc(NN);
    int*   fill   = (int*)alloc(NN);
    int*   bsum   = (int*)alloc(SCAN_B);
    int*   csrs   = (int*)alloc(NE);
    float* csrw   = alloc(NE);
    int*   gstart = (int*)alloc(NG + 1);
    float* H      = alloc((size_t)MP * HD);               // f32 final-layer features (pool)
    h16*   x16    = (h16*)alloc((size_t)MP * FIN / 2);    // fp16 x
    h16*   hi0    = (h16*)alloc((size_t)MP * KPAD / 2);   // fp16 Tx0 (in-place per layer)
    h16*   hi1    = (h16*)alloc((size_t)MP * KPAD / 2);   // fp16 Tx1
    h16*   hi2    = (h16*)alloc((size_t)MP * KPAD / 2);   // fp16 Tx2
    const int WSZ0 = 3 * 2 * 208 * 32;                    // layer 0 (fin=64, ksteps=2)
    const int WSZ  = 3 * 7 * 208 * 32;                    // layers 1-3 (fin=200, ksteps=7)
    h16* wt0 = (h16*)alloc(WSZ0 / 2);
    h16* wt1 = (h16*)alloc(WSZ / 2);
    h16* wt2 = (h16*)alloc(WSZ / 2);
    h16* wt3 = (h16*)alloc(WSZ / 2);

    dim3 blk(256);
    int gE = (E + 255) / 256;
    int gN = (n + 255) / 256;
    int gScan = (n + SCAN_B - 1) / SCAN_B;
    int gN16 = (n + 15) / 16;     // 16 nodes per block (16-lane groups)
    int gGemm = MP / 64;          // 782 blocks, 4 waves x 16 rows

    // --- W pre-transpose (L2-resident fp16 fragments) + x fp16 + bounds ---
    k_wprep<<<(WSZ0 + 255) / 256, blk, 0, stream>>>(W1, wt0, FIN, 2, WSZ0);
    k_wprep<<<(WSZ + 255) / 256, blk, 0, stream>>>(W2, wt1, HD, 7, WSZ);
    k_wprep<<<(WSZ + 255) / 256, blk, 0, stream>>>(W3, wt2, HD, 7, WSZ);
    k_wprep<<<(WSZ + 255) / 256, blk, 0, stream>>>(W4, wt3, HD, 7, WSZ);
    k_split<<<(NN * FIN + 255) / 256, blk, 0, stream>>>(x, x16, NN * FIN);
    k_bounds<<<2, blk, 0, stream>>>(batch, gstart, n);
    // hi0 pads (cols 200..223 + tail rows) must be zero: gemm only writes cols<200
    hipMemsetAsync(hi0, 0, (size_t)MP * KPAD * 2, stream);

    // --- normalization + CSR build ---
    hipMemsetAsync(dis, 0, (size_t)NN * 4, stream);
    hipMemsetAsync(cntd, 0, (size_t)NN * 4, stream);
    hipMemsetAsync(fill, 0, (size_t)NN * 4, stream);
    k_deg<<<gE, blk, 0, stream>>>(src, dst, dis, cntd, E);
    k_node_prep<<<gN, blk, 0, stream>>>(dis, batch, lmax, diag, n);
    k_edge_w<<<gE, blk, 0, stream>>>(src, dst, batch, lmax, dis, wE, E);
    k_scan1<<<gScan, blk, 0, stream>>>(cntd, rowst, bsum, n);
    k_scan2<<<1, blk, 0, stream>>>(bsum, gScan);
    k_scan3<<<gScan, blk, 0, stream>>>(rowst, bsum, n);
    k_fillcsr<<<gE, blk, 0, stream>>>(src, dst, wE, rowst, fill, csrs, csrw, E);

    // --- 4 Chebyshev layers ---
    const h16* wt[4] = {wt0, wt1, wt2, wt3};
    const float* bl[4] = {b1, b2, b3, b4};
    for (int l = 0; l < 4; l++) {
        int s16 = (l == 0) ? FIN : KPAD;
        int CW = (l == 0) ? 64 : 56;
        int nch = (l == 0) ? 1 : 4;
        int ksteps = (l == 0) ? 2 : 7;
        const h16* a0 = (l == 0) ? x16 : hi0;
        dim3 gg(gN16, nch);
        // Tx1 = prop(Tx0) -> hi1
        k_gather<<<gg, blk, 0, stream>>>(rowst, cntd, csrs, csrw, diag, a0, a0, hi1, s16, CW, n, 0);
        // Tx2 = 2*prop(Tx1) - Tx0 -> hi2
        k_gather<<<gg, blk, 0, stream>>>(rowst, cntd, csrs, csrw, diag, hi1, a0, hi2, s16, CW, n, 1);
        // out = relu([Tx0|Tx1|Tx2] @ W + b)
        k_gemm16<<<gGemm, blk, 0, stream>>>(a0, hi1, hi2, s16, ksteps, wt[l], bl[l],
                                            (l == 3) ? H : nullptr,
                                            (l < 3) ? hi0 : nullptr, n);
    }

    // --- fused pool + FC head (no atomics; batch is sorted) ---
    k_pool_fc<<<NG, blk, 0, stream>>>(H, gstart, fcw, fcb, out);
}